// Round 6
// baseline (722.173 us; speedup 1.0000x reference)
//
#include <hip/hip_runtime.h>

typedef __attribute__((ext_vector_type(8))) short bf16x8;
typedef __attribute__((ext_vector_type(4))) float f32x4;
typedef unsigned short u16;
typedef unsigned int u32;

#define SCALE_ 0.17677669529663687f   // 32^-0.5
#define MFMA(a,b,c) __builtin_amdgcn_mfma_f32_16x16x32_bf16(a,b,c,0,0,0)

__device__ __forceinline__ u16 f2bf(float f){
    u32 u = __float_as_uint(f);
    u = (u + 0x7FFFu + ((u >> 16) & 1u)) >> 16;
    return (u16)u;
}
__device__ __forceinline__ float bf2f(u32 h){ return __uint_as_float(h << 16); }
__device__ __forceinline__ u32 pk2(float a, float b){ return (u32)f2bf(a) | ((u32)f2bf(b) << 16); }

// Build an 8-element (K-octet) MFMA fragment from packed C-tiles via shuffles.
// fragment[l15][kg*8+reg] = Ctilepair[row = kg*8+reg][col = l15], where p0 holds
// rows 0-15 and p1 rows 16-31 (regs packed as uint2{(r0,r1),(r2,r3)}).
__device__ __forceinline__ bf16x8 frag8(uint2 p0, uint2 p1, int kg, int l15){
    const int s0 = ((kg & 1) << 5) + l15;
    const int s1 = s0 + 16;
    u32 a0 = (u32)__shfl((int)p0.x, s0, 64);
    u32 a1 = (u32)__shfl((int)p0.y, s0, 64);
    u32 a2 = (u32)__shfl((int)p0.x, s1, 64);
    u32 a3 = (u32)__shfl((int)p0.y, s1, 64);
    u32 b0 = (u32)__shfl((int)p1.x, s0, 64);
    u32 b1 = (u32)__shfl((int)p1.y, s0, 64);
    u32 b2 = (u32)__shfl((int)p1.x, s1, 64);
    u32 b3 = (u32)__shfl((int)p1.y, s1, 64);
    const bool hi = (kg >= 2);
    union { u32 u[4]; bf16x8 v; } r;
    r.u[0] = hi ? b0 : a0; r.u[1] = hi ? b1 : a1;
    r.u[2] = hi ? b2 : a2; r.u[3] = hi ? b3 : a3;
    return r.v;
}

// ws layout (u16 units):
//   [0,      65536)  Wq rows   [d][c] row-major
//   [65536, 131072)  Wk rows
//   [131072,196608)  WvT packed per head: h*8192 + ((c>>3)*32 + hd)*8 + (c&7)
//   [196608,262144)  Wproj rows
//   [262144,263424)  rpe_pk: (j*8 + h)*32 + hd
//   [263424,263680)  w1_pk:  h*32 + hd
__global__ void prep_kernel(const float* __restrict__ Wkv, const float* __restrict__ Wq,
                            const float* __restrict__ Wproj, const float* __restrict__ rpe,
                            const float* __restrict__ w1, u16* __restrict__ wpk)
{
    int i = blockIdx.x * 256 + threadIdx.x;
    if (i < 65536)        wpk[i] = f2bf(Wq[i]);
    else if (i < 131072)  wpk[i] = f2bf(Wkv[i - 65536]);
    else if (i < 196608){
        int j = i - 131072;
        int h = j >> 13;
        int r = j & 8191;
        int coct = r >> 8;
        int hd   = (r >> 3) & 31;
        int clo  = r & 7;
        wpk[i] = f2bf(Wkv[(size_t)(256 + h*32 + hd) * 256 + coct*8 + clo]);
    }
    else if (i < 262144)  wpk[i] = f2bf(Wproj[i - 196608]);
    else if (i < 263424){
        int j = i - 262144;
        int jj = j >> 8, h = (j >> 5) & 7, hd = j & 31;
        wpk[i] = f2bf(rpe[jj*256 + h*32 + hd]);
    }
    else if (i < 263680)  wpk[i] = f2bf(w1[i - 263424]);
}

// One block per (n,t). 8 waves; each wave owns ONE head end-to-end (no barriers
// inside the head pipeline). 2 block barriers total. 4 blocks/CU -> 32 waves.
__launch_bounds__(512, 8)
__global__ void mhsa_main(const float* __restrict__ x, const float* __restrict__ e,
                          const float* __restrict__ outer, const float* __restrict__ alpha,
                          const float* __restrict__ bproj, const u16* __restrict__ wpk,
                          float* __restrict__ out)
{
    // xs/es/opk: [c>>3][node pitch 26][c&7] bf16, 13312 B each (+pad for tail reads)
    __shared__ __align__(16) u16 smem[6656*3 + 64];
    u16* xs  = smem;
    u16* es  = smem + 6656;
    u16* opk = smem + 13312;

    const int tid = threadIdx.x;
    const int w = tid >> 6, lane = tid & 63;
    const int l15 = lane & 15, kg = lane >> 4;
    // XCD-chunked swizzle (bijective: 3840 % 8 == 0): each XCD gets a
    // contiguous (n,t) range so t-adjacent partial cache lines stay local.
    const int wg = (blockIdx.x & 7) * 480 + (blockIdx.x >> 3);
    const int n = wg / 120, t = wg % 120;
    const float alpha0 = alpha[0];
    const f32x4 zf = {0.f, 0.f, 0.f, 0.f};

    // ---- stage x, e (bf16, K-packed) ----
    const float* xb = x + (size_t)n*768000 + t*25;
    const float* eb = e + (size_t)n*768000 + t*25;
    for (int i = tid; i < 6400; i += 512){
        int c = i / 25, v = i - c*25;
        int a16 = ((c>>3)*26 + v)*8 + (c&7);
        xs[a16] = f2bf(xb[c*3000 + v]);
        es[a16] = f2bf(eb[c*3000 + v]);
    }
    __syncthreads();

    {
        const int h = w;   // one head per wave

        // ===== q,k GEMM: M=32(hd) N=32(node) K=256 =====
        f32x4 cq[2][2], ck[2][2];
        #pragma unroll
        for (int i = 0; i < 2; ++i)
            #pragma unroll
            for (int j = 0; j < 2; ++j){ cq[i][j] = zf; ck[i][j] = zf; }
        {
            const u16* wq0 = wpk + (size_t)(h*32 + l15)*256;
            const u16* wk0 = wpk + 65536 + (size_t)(h*32 + l15)*256;
            #pragma unroll
            for (int ks = 0; ks < 8; ++ks){
                bf16x8 b0 = *(const bf16x8*)&xs[((ks*4+kg)*26 + l15)*8];
                bf16x8 b1 = *(const bf16x8*)&xs[((ks*4+kg)*26 + 16 + l15)*8];
                bf16x8 aq0 = *(const bf16x8*)(wq0 + ks*32 + kg*8);
                bf16x8 aq1 = *(const bf16x8*)(wq0 + 4096 + ks*32 + kg*8);
                bf16x8 ak0 = *(const bf16x8*)(wk0 + ks*32 + kg*8);
                bf16x8 ak1 = *(const bf16x8*)(wk0 + 4096 + ks*32 + kg*8);
                cq[0][0]=MFMA(aq0,b0,cq[0][0]); cq[0][1]=MFMA(aq0,b1,cq[0][1]);
                cq[1][0]=MFMA(aq1,b0,cq[1][0]); cq[1][1]=MFMA(aq1,b1,cq[1][1]);
                ck[0][0]=MFMA(ak0,b0,ck[0][0]); ck[0][1]=MFMA(ak0,b1,ck[0][1]);
                ck[1][0]=MFMA(ak1,b0,ck[1][0]); ck[1][1]=MFMA(ak1,b1,ck[1][1]);
            }
        }
        // e-add into ck (KE = k + e_k) and pack q,k C-tiles
        uint2 P_q[2][2], P_k[2][2];
        #pragma unroll
        for (int mt = 0; mt < 2; ++mt)
            #pragma unroll
            for (int nt = 0; nt < 2; ++nt){
                int coct = h*4 + mt*2 + (kg>>1);
                uint2 ev = *(const uint2*)&es[(coct*26 + nt*16 + l15)*8 + (kg&1)*4];
                ck[mt][nt][0] += bf2f(ev.x & 0xFFFFu);
                ck[mt][nt][1] += bf2f(ev.x >> 16);
                ck[mt][nt][2] += bf2f(ev.y & 0xFFFFu);
                ck[mt][nt][3] += bf2f(ev.y >> 16);
                uint2 pq; pq.x = pk2(cq[mt][nt][0], cq[mt][nt][1]);
                pq.y = pk2(cq[mt][nt][2], cq[mt][nt][3]);
                P_q[nt][mt] = pq;
                uint2 pk; pk.x = pk2(ck[mt][nt][0], ck[mt][nt][1]);
                pk.y = pk2(ck[mt][nt][2], ck[mt][nt][3]);
                P_k[nt][mt] = pk;
            }

        // ===== bias[b] = w1_h . e_k[:,b] via broadcast-A MFMA =====
        float bias01[2];
        {
            bf16x8 aw1 = *(const bf16x8*)(wpk + 263424 + h*32 + kg*8);
            bf16x8 be0 = *(const bf16x8*)&es[((h*4+kg)*26 + l15)*8];
            bf16x8 be1 = *(const bf16x8*)&es[((h*4+kg)*26 + 16 + l15)*8];
            f32x4 cb0 = MFMA(aw1, be0, zf);
            f32x4 cb1 = MFMA(aw1, be1, zf);
            bias01[0] = cb0[0]; bias01[1] = cb1[0];
        }

        // ===== v GEMM transposed: C[node][hd] = x^T @ Wv^T =====
        f32x4 cv[2][2];
        #pragma unroll
        for (int i = 0; i < 2; ++i)
            #pragma unroll
            for (int j = 0; j < 2; ++j) cv[i][j] = zf;
        {
            const u16* wvt = wpk + 131072 + h*8192;
            #pragma unroll
            for (int ks = 0; ks < 8; ++ks){
                bf16x8 a0 = *(const bf16x8*)&xs[((ks*4+kg)*26 + l15)*8];
                bf16x8 a1 = *(const bf16x8*)&xs[((ks*4+kg)*26 + 16 + l15)*8];
                bf16x8 bv0 = *(const bf16x8*)&wvt[((ks*4+kg)*32 + l15)*8];
                bf16x8 bv1 = *(const bf16x8*)&wvt[((ks*4+kg)*32 + 16 + l15)*8];
                cv[0][0]=MFMA(a0,bv0,cv[0][0]); cv[0][1]=MFMA(a0,bv1,cv[0][1]);
                cv[1][0]=MFMA(a1,bv0,cv[1][0]); cv[1][1]=MFMA(a1,bv1,cv[1][1]);
            }
        }
        // CRITICAL: zero v rows node>=25 (garbage/NaN from LDS over-read).
        // These become K-columns of the PV A-operand; NaN*0 would poison all
        // output rows (R4 failure mode).
        #pragma unroll
        for (int nt = 0; nt < 2; ++nt)
            #pragma unroll
            for (int r = 0; r < 4; ++r)
                cv[1][nt][r] = (kg*4 + r < 9) ? cv[1][nt][r] : 0.f;

        uint2 P_v[2][2];
        #pragma unroll
        for (int mt = 0; mt < 2; ++mt)
            #pragma unroll
            for (int nt = 0; nt < 2; ++nt){
                uint2 pv; pv.x = pk2(cv[mt][nt][0], cv[mt][nt][1]);
                pv.y = pk2(cv[mt][nt][2], cv[mt][nt][3]);
                P_v[nt][mt] = pv;
            }

        // ===== scores: S^T[b][a] = KE[b][hd] @ q^T[hd][a], K=32 =====
        bf16x8 fq0  = frag8(P_q[0][0], P_q[0][1], kg, l15);
        bf16x8 fq1  = frag8(P_q[1][0], P_q[1][1], kg, l15);
        bf16x8 fke0 = frag8(P_k[0][0], P_k[0][1], kg, l15);
        bf16x8 fke1 = frag8(P_k[1][0], P_k[1][1], kg, l15);
        if (l15 >= 9){   // rows b=25..29: rpe vectors; b=30,31: zero
            if (l15 <= 13)
                fke1 = *(const bf16x8*)(wpk + 262144 + ((l15-9)*8 + h)*32 + kg*8);
            else {
                union { u32 u[4]; bf16x8 v; } z; z.u[0]=z.u[1]=z.u[2]=z.u[3]=0;
                fke1 = z.v;
            }
        }
        f32x4 sc[2][2];
        sc[0][0] = MFMA(fke0, fq0, zf);
        sc[0][1] = MFMA(fke0, fq1, zf);
        sc[1][0] = MFMA(fke1, fq0, zf);
        sc[1][1] = MFMA(fke1, fq1, zf);

        // ===== softmax over b (per column a), fuse alpha*P + outer =====
        uint2 P_G[2][2];
        #pragma unroll
        for (int nt = 0; nt < 2; ++nt){
            const int a = nt*16 + l15;
            f32x4 s0 = sc[0][nt], s1 = sc[1][nt];
            // R[j][a] lives in S^T rows 25+j -> (kg,r): j0:(2,1) j1:(2,2) j2:(2,3) j3:(3,0) j4:(3,1)
            float rr0 = __shfl(s1[1], 32 + l15, 64);
            float rr1 = __shfl(s1[2], 32 + l15, 64);
            float rr2 = __shfl(s1[3], 32 + l15, 64);
            float rr3 = __shfl(s1[0], 48 + l15, 64);
            float rr4 = __shfl(s1[1], 48 + l15, 64);
            float tv[8];
            #pragma unroll
            for (int mt = 0; mt < 2; ++mt)
                #pragma unroll
                for (int r = 0; r < 4; ++r){
                    int b = mt*16 + kg*4 + r;
                    float sval = mt ? s1[r] : s0[r];
                    float bb = __shfl(bias01[mt], (lane & 48) + (b & 15), 64);
                    int d = a - b; d = d < 0 ? -d : d; if (d > 4) d = 4;
                    float rj = d==0?rr0 : d==1?rr1 : d==2?rr2 : d==3?rr3 : rr4;
                    float tt = (sval + rj + bb) * SCALE_;
                    tv[mt*4+r] = (b < 25) ? tt : -1e30f;
                }
            float m = tv[0];
            #pragma unroll
            for (int i = 1; i < 8; ++i) m = fmaxf(m, tv[i]);
            m = fmaxf(m, __shfl_xor(m, 16, 64));
            m = fmaxf(m, __shfl_xor(m, 32, 64));
            float ex[8], sm = 0.f;
            #pragma unroll
            for (int i = 0; i < 8; ++i){ ex[i] = __expf(tv[i] - m); sm += ex[i]; }
            sm += __shfl_xor(sm, 16, 64);
            sm += __shfl_xor(sm, 32, 64);
            const float inv = alpha0 / sm;
            float g[8];
            #pragma unroll
            for (int mt = 0; mt < 2; ++mt)
                #pragma unroll
                for (int r = 0; r < 4; ++r){
                    int b = mt*16 + kg*4 + r;
                    float ov = (a < 25 && b < 25) ? outer[((size_t)h*25 + a)*25 + b] : 0.f;
                    g[mt*4+r] = (b < 25) ? ex[mt*4+r]*inv + ov : 0.f;
                }
            uint2 pg0; pg0.x = pk2(g[0], g[1]); pg0.y = pk2(g[2], g[3]);
            uint2 pg1; pg1.x = pk2(g[4], g[5]); pg1.y = pk2(g[6], g[7]);
            P_G[nt][0] = pg0; P_G[nt][1] = pg1;
        }

        // ===== PV: C[hd][a] = v^T[hd][b] @ G^T[b][a], K=32 =====
        {
            bf16x8 fv0 = frag8(P_v[0][0], P_v[0][1], kg, l15);
            bf16x8 fv1 = frag8(P_v[1][0], P_v[1][1], kg, l15);
            bf16x8 fg0 = frag8(P_G[0][0], P_G[0][1], kg, l15);
            bf16x8 fg1 = frag8(P_G[1][0], P_G[1][1], kg, l15);
            f32x4 o[2][2];
            o[0][0] = MFMA(fv0, fg0, zf); o[0][1] = MFMA(fv0, fg1, zf);
            o[1][0] = MFMA(fv1, fg0, zf); o[1][1] = MFMA(fv1, fg1, zf);
            #pragma unroll
            for (int mt = 0; mt < 2; ++mt)
                #pragma unroll
                for (int nt = 0; nt < 2; ++nt){
                    int a = nt*16 + l15;
                    if (a < 25){
                        int coct = h*4 + mt*2 + (kg>>1);
                        u32* dst = (u32*)&opk[(coct*26 + a)*8 + (kg&1)*4];
                        dst[0] = pk2(o[mt][nt][0], o[mt][nt][1]);
                        dst[1] = pk2(o[mt][nt][2], o[mt][nt][3]);
                    }
                }
        }
    }
    __syncthreads();

    // ===== proj: out = Wproj @ o + bproj, K=256, cooperative (32 d per wave) =====
    {
        f32x4 pc[2][2];
        #pragma unroll
        for (int i = 0; i < 2; ++i){ pc[i][0] = zf; pc[i][1] = zf; }
        #pragma unroll
        for (int ks = 0; ks < 8; ++ks){
            bf16x8 pb0 = *(const bf16x8*)&opk[((ks*4+kg)*26 + l15)*8];
            bf16x8 pb1 = *(const bf16x8*)&opk[((ks*4+kg)*26 + 16 + l15)*8];
            #pragma unroll
            for (int i = 0; i < 2; ++i){
                bf16x8 aw = *(const bf16x8*)(wpk + 196608 +
                                (size_t)(w*32 + i*16 + l15)*256 + ks*32 + kg*8);
                pc[i][0] = MFMA(aw, pb0, pc[i][0]);
                pc[i][1] = MFMA(aw, pb1, pc[i][1]);
            }
        }
        #pragma unroll
        for (int i = 0; i < 2; ++i){
            const int d = w*32 + i*16 + kg*4;
            float b0 = bproj[d], b1 = bproj[d+1], b2 = bproj[d+2], b3 = bproj[d+3];
            #pragma unroll
            for (int nt = 0; nt < 2; ++nt){
                int v = nt*16 + l15;
                if (v < 25){
                    float* op = out + (size_t)n*768000 + (size_t)d*3000 + t*25 + v;
                    op[0]    = pc[i][nt][0] + b0;
                    op[3000] = pc[i][nt][1] + b1;
                    op[6000] = pc[i][nt][2] + b2;
                    op[9000] = pc[i][nt][3] + b3;
                }
            }
        }
    }
}

extern "C" void kernel_launch(void* const* d_in, const int* in_sizes, int n_in,
                              void* d_out, int out_size, void* d_ws, size_t ws_size,
                              hipStream_t stream) {
    (void)in_sizes; (void)n_in; (void)out_size; (void)ws_size;
    const float* x     = (const float*)d_in[0];
    const float* e     = (const float*)d_in[1];
    const float* Wkv   = (const float*)d_in[2];
    const float* Wq    = (const float*)d_in[3];
    const float* Wproj = (const float*)d_in[4];
    const float* bproj = (const float*)d_in[5];
    const float* rpe   = (const float*)d_in[6];
    const float* w1    = (const float*)d_in[7];
    const float* outer = (const float*)d_in[8];
    const float* alpha = (const float*)d_in[9];
    float* out = (float*)d_out;
    u16* wpk = (u16*)d_ws;

    prep_kernel<<<1030, 256, 0, stream>>>(Wkv, Wq, Wproj, rpe, w1, wpk);
    mhsa_main<<<32*120, 512, 0, stream>>>(x, e, outer, alpha, bproj, wpk, out);
}

// Round 7
// 303.078 us; speedup vs baseline: 2.3828x; 2.3828x over previous
//
#include <hip/hip_runtime.h>

typedef __attribute__((ext_vector_type(8))) short bf16x8;
typedef __attribute__((ext_vector_type(4))) float f32x4;
typedef unsigned short u16;
typedef unsigned int u32;

#define SCALE_ 0.17677669529663687f   // 32^-0.5
#define MFMA(a,b,c) __builtin_amdgcn_mfma_f32_16x16x32_bf16(a,b,c,0,0,0)

__device__ __forceinline__ u16 f2bf(float f){
    u32 u = __float_as_uint(f);
    u = (u + 0x7FFFu + ((u >> 16) & 1u)) >> 16;
    return (u16)u;
}
__device__ __forceinline__ float bf2f(u32 h){ return __uint_as_float(h << 16); }
__device__ __forceinline__ u32 pk2(float a, float b){ return (u32)f2bf(a) | ((u32)f2bf(b) << 16); }

// Build an 8-element (K-octet) MFMA fragment from packed C-tiles via shuffles.
// fragment[l15][kg*8+reg] = Ctilepair[row = kg*8+reg][col = l15], where p0 holds
// rows 0-15 and p1 rows 16-31 (regs packed as uint2{(r0,r1),(r2,r3)}).
__device__ __forceinline__ bf16x8 frag8(uint2 p0, uint2 p1, int kg, int l15){
    const int s0 = ((kg & 1) << 5) + l15;
    const int s1 = s0 + 16;
    u32 a0 = (u32)__shfl((int)p0.x, s0, 64);
    u32 a1 = (u32)__shfl((int)p0.y, s0, 64);
    u32 a2 = (u32)__shfl((int)p0.x, s1, 64);
    u32 a3 = (u32)__shfl((int)p0.y, s1, 64);
    u32 b0 = (u32)__shfl((int)p1.x, s0, 64);
    u32 b1 = (u32)__shfl((int)p1.y, s0, 64);
    u32 b2 = (u32)__shfl((int)p1.x, s1, 64);
    u32 b3 = (u32)__shfl((int)p1.y, s1, 64);
    const bool hi = (kg >= 2);
    union { u32 u[4]; bf16x8 v; } r;
    r.u[0] = hi ? b0 : a0; r.u[1] = hi ? b1 : a1;
    r.u[2] = hi ? b2 : a2; r.u[3] = hi ? b3 : a3;
    return r.v;
}

// ws layout (u16 units):
//   [0,      65536)  Wq rows   [d][c] row-major
//   [65536, 131072)  Wk rows
//   [131072,196608)  WvT packed per head: h*8192 + ((c>>3)*32 + hd)*8 + (c&7)
//   [196608,262144)  Wproj rows
//   [262144,263424)  rpe_pk: (j*8 + h)*32 + hd
//   [263424,263680)  w1_pk:  h*32 + hd
__global__ void prep_kernel(const float* __restrict__ Wkv, const float* __restrict__ Wq,
                            const float* __restrict__ Wproj, const float* __restrict__ rpe,
                            const float* __restrict__ w1, u16* __restrict__ wpk)
{
    int i = blockIdx.x * 256 + threadIdx.x;
    if (i < 65536)        wpk[i] = f2bf(Wq[i]);
    else if (i < 131072)  wpk[i] = f2bf(Wkv[i - 65536]);
    else if (i < 196608){
        int j = i - 131072;
        int h = j >> 13;
        int r = j & 8191;
        int coct = r >> 8;
        int hd   = (r >> 3) & 31;
        int clo  = r & 7;
        wpk[i] = f2bf(Wkv[(size_t)(256 + h*32 + hd) * 256 + coct*8 + clo]);
    }
    else if (i < 262144)  wpk[i] = f2bf(Wproj[i - 196608]);
    else if (i < 263424){
        int j = i - 262144;
        int jj = j >> 8, h = (j >> 5) & 7, hd = j & 31;
        wpk[i] = f2bf(rpe[jj*256 + h*32 + hd]);
    }
    else if (i < 263680)  wpk[i] = f2bf(w1[i - 263424]);
}

// One block per (n,t). 8 waves; each wave owns ONE head end-to-end (no barriers
// inside the head pipeline). 2 block barriers total.
// (512,4): 2 blocks/CU (LDS 81KB), 16 waves/CU, VGPR cap 128 (no spills --
// R6's (512,8) forced VGPR=32 and 1.3GB of scratch traffic).
__launch_bounds__(512, 4)
__global__ void mhsa_main(const float* __restrict__ x, const float* __restrict__ e,
                          const float* __restrict__ outer, const float* __restrict__ alpha,
                          const float* __restrict__ bproj, const u16* __restrict__ wpk,
                          float* __restrict__ out)
{
    // xs/es/opk: [c>>3][node pitch 26][c&7] bf16, 13312 B each (+pad for tail reads)
    __shared__ __align__(16) u16 smem[6656*3 + 64];
    u16* xs  = smem;
    u16* es  = smem + 6656;
    u16* opk = smem + 13312;

    const int tid = threadIdx.x;
    const int w = tid >> 6, lane = tid & 63;
    const int l15 = lane & 15, kg = lane >> 4;
    // XCD-chunked swizzle (bijective: 3840 % 8 == 0): each XCD gets a
    // contiguous (n,t) range so t-adjacent partial cache lines stay local.
    const int wg = (blockIdx.x & 7) * 480 + (blockIdx.x >> 3);
    const int n = wg / 120, t = wg % 120;
    const float alpha0 = alpha[0];
    const f32x4 zf = {0.f, 0.f, 0.f, 0.f};

    // ---- stage x, e (bf16, K-packed) ----
    const float* xb = x + (size_t)n*768000 + t*25;
    const float* eb = e + (size_t)n*768000 + t*25;
    for (int i = tid; i < 6400; i += 512){
        int c = i / 25, v = i - c*25;
        int a16 = ((c>>3)*26 + v)*8 + (c&7);
        xs[a16] = f2bf(xb[c*3000 + v]);
        es[a16] = f2bf(eb[c*3000 + v]);
    }
    __syncthreads();

    {
        const int h = w;   // one head per wave

        // ===== q,k GEMM: M=32(hd) N=32(node) K=256 =====
        f32x4 cq[2][2], ck[2][2];
        #pragma unroll
        for (int i = 0; i < 2; ++i)
            #pragma unroll
            for (int j = 0; j < 2; ++j){ cq[i][j] = zf; ck[i][j] = zf; }
        {
            const u16* wq0 = wpk + (size_t)(h*32 + l15)*256;
            const u16* wk0 = wpk + 65536 + (size_t)(h*32 + l15)*256;
            #pragma unroll
            for (int ks = 0; ks < 8; ++ks){
                bf16x8 b0 = *(const bf16x8*)&xs[((ks*4+kg)*26 + l15)*8];
                bf16x8 b1 = *(const bf16x8*)&xs[((ks*4+kg)*26 + 16 + l15)*8];
                bf16x8 aq0 = *(const bf16x8*)(wq0 + ks*32 + kg*8);
                bf16x8 aq1 = *(const bf16x8*)(wq0 + 4096 + ks*32 + kg*8);
                bf16x8 ak0 = *(const bf16x8*)(wk0 + ks*32 + kg*8);
                bf16x8 ak1 = *(const bf16x8*)(wk0 + 4096 + ks*32 + kg*8);
                cq[0][0]=MFMA(aq0,b0,cq[0][0]); cq[0][1]=MFMA(aq0,b1,cq[0][1]);
                cq[1][0]=MFMA(aq1,b0,cq[1][0]); cq[1][1]=MFMA(aq1,b1,cq[1][1]);
                ck[0][0]=MFMA(ak0,b0,ck[0][0]); ck[0][1]=MFMA(ak0,b1,ck[0][1]);
                ck[1][0]=MFMA(ak1,b0,ck[1][0]); ck[1][1]=MFMA(ak1,b1,ck[1][1]);
            }
        }
        // e-add into ck (KE = k + e_k) and pack q,k C-tiles
        uint2 P_q[2][2], P_k[2][2];
        #pragma unroll
        for (int mt = 0; mt < 2; ++mt)
            #pragma unroll
            for (int nt = 0; nt < 2; ++nt){
                int coct = h*4 + mt*2 + (kg>>1);
                uint2 ev = *(const uint2*)&es[(coct*26 + nt*16 + l15)*8 + (kg&1)*4];
                ck[mt][nt][0] += bf2f(ev.x & 0xFFFFu);
                ck[mt][nt][1] += bf2f(ev.x >> 16);
                ck[mt][nt][2] += bf2f(ev.y & 0xFFFFu);
                ck[mt][nt][3] += bf2f(ev.y >> 16);
                uint2 pq; pq.x = pk2(cq[mt][nt][0], cq[mt][nt][1]);
                pq.y = pk2(cq[mt][nt][2], cq[mt][nt][3]);
                P_q[nt][mt] = pq;
                uint2 pk; pk.x = pk2(ck[mt][nt][0], ck[mt][nt][1]);
                pk.y = pk2(ck[mt][nt][2], ck[mt][nt][3]);
                P_k[nt][mt] = pk;
            }

        // ===== bias[b] = w1_h . e_k[:,b] via broadcast-A MFMA =====
        float bias01[2];
        {
            bf16x8 aw1 = *(const bf16x8*)(wpk + 263424 + h*32 + kg*8);
            bf16x8 be0 = *(const bf16x8*)&es[((h*4+kg)*26 + l15)*8];
            bf16x8 be1 = *(const bf16x8*)&es[((h*4+kg)*26 + 16 + l15)*8];
            f32x4 cb0 = MFMA(aw1, be0, zf);
            f32x4 cb1 = MFMA(aw1, be1, zf);
            bias01[0] = cb0[0]; bias01[1] = cb1[0];
        }

        // ===== v GEMM transposed: C[node][hd] = x^T @ Wv^T =====
        f32x4 cv[2][2];
        #pragma unroll
        for (int i = 0; i < 2; ++i)
            #pragma unroll
            for (int j = 0; j < 2; ++j) cv[i][j] = zf;
        {
            const u16* wvt = wpk + 131072 + h*8192;
            #pragma unroll
            for (int ks = 0; ks < 8; ++ks){
                bf16x8 a0 = *(const bf16x8*)&xs[((ks*4+kg)*26 + l15)*8];
                bf16x8 a1 = *(const bf16x8*)&xs[((ks*4+kg)*26 + 16 + l15)*8];
                bf16x8 bv0 = *(const bf16x8*)&wvt[((ks*4+kg)*32 + l15)*8];
                bf16x8 bv1 = *(const bf16x8*)&wvt[((ks*4+kg)*32 + 16 + l15)*8];
                cv[0][0]=MFMA(a0,bv0,cv[0][0]); cv[0][1]=MFMA(a0,bv1,cv[0][1]);
                cv[1][0]=MFMA(a1,bv0,cv[1][0]); cv[1][1]=MFMA(a1,bv1,cv[1][1]);
            }
        }
        // CRITICAL: zero v rows node>=25 (garbage/NaN from LDS over-read).
        // These become K-columns of the PV A-operand; NaN*0 would poison all
        // output rows (R4 failure mode).
        #pragma unroll
        for (int nt = 0; nt < 2; ++nt)
            #pragma unroll
            for (int r = 0; r < 4; ++r)
                cv[1][nt][r] = (kg*4 + r < 9) ? cv[1][nt][r] : 0.f;

        uint2 P_v[2][2];
        #pragma unroll
        for (int mt = 0; mt < 2; ++mt)
            #pragma unroll
            for (int nt = 0; nt < 2; ++nt){
                uint2 pv; pv.x = pk2(cv[mt][nt][0], cv[mt][nt][1]);
                pv.y = pk2(cv[mt][nt][2], cv[mt][nt][3]);
                P_v[nt][mt] = pv;
            }

        // ===== scores: S^T[b][a] = KE[b][hd] @ q^T[hd][a], K=32 =====
        bf16x8 fq0  = frag8(P_q[0][0], P_q[0][1], kg, l15);
        bf16x8 fq1  = frag8(P_q[1][0], P_q[1][1], kg, l15);
        bf16x8 fke0 = frag8(P_k[0][0], P_k[0][1], kg, l15);
        bf16x8 fke1 = frag8(P_k[1][0], P_k[1][1], kg, l15);
        if (l15 >= 9){   // rows b=25..29: rpe vectors; b=30,31: zero
            if (l15 <= 13)
                fke1 = *(const bf16x8*)(wpk + 262144 + ((l15-9)*8 + h)*32 + kg*8);
            else {
                union { u32 u[4]; bf16x8 v; } z; z.u[0]=z.u[1]=z.u[2]=z.u[3]=0;
                fke1 = z.v;
            }
        }
        f32x4 sc[2][2];
        sc[0][0] = MFMA(fke0, fq0, zf);
        sc[0][1] = MFMA(fke0, fq1, zf);
        sc[1][0] = MFMA(fke1, fq0, zf);
        sc[1][1] = MFMA(fke1, fq1, zf);

        // ===== softmax over b (per column a), fuse alpha*P + outer =====
        uint2 P_G[2][2];
        #pragma unroll
        for (int nt = 0; nt < 2; ++nt){
            const int a = nt*16 + l15;
            f32x4 s0 = sc[0][nt], s1 = sc[1][nt];
            // R[j][a] lives in S^T rows 25+j -> (kg,r): j0:(2,1) j1:(2,2) j2:(2,3) j3:(3,0) j4:(3,1)
            float rr0 = __shfl(s1[1], 32 + l15, 64);
            float rr1 = __shfl(s1[2], 32 + l15, 64);
            float rr2 = __shfl(s1[3], 32 + l15, 64);
            float rr3 = __shfl(s1[0], 48 + l15, 64);
            float rr4 = __shfl(s1[1], 48 + l15, 64);
            float tv[8];
            #pragma unroll
            for (int mt = 0; mt < 2; ++mt)
                #pragma unroll
                for (int r = 0; r < 4; ++r){
                    int b = mt*16 + kg*4 + r;
                    float sval = mt ? s1[r] : s0[r];
                    float bb = __shfl(bias01[mt], (lane & 48) + (b & 15), 64);
                    int d = a - b; d = d < 0 ? -d : d; if (d > 4) d = 4;
                    float rj = d==0?rr0 : d==1?rr1 : d==2?rr2 : d==3?rr3 : rr4;
                    float tt = (sval + rj + bb) * SCALE_;
                    tv[mt*4+r] = (b < 25) ? tt : -1e30f;
                }
            float m = tv[0];
            #pragma unroll
            for (int i = 1; i < 8; ++i) m = fmaxf(m, tv[i]);
            m = fmaxf(m, __shfl_xor(m, 16, 64));
            m = fmaxf(m, __shfl_xor(m, 32, 64));
            float ex[8], sm = 0.f;
            #pragma unroll
            for (int i = 0; i < 8; ++i){ ex[i] = __expf(tv[i] - m); sm += ex[i]; }
            sm += __shfl_xor(sm, 16, 64);
            sm += __shfl_xor(sm, 32, 64);
            const float inv = alpha0 / sm;
            float g[8];
            #pragma unroll
            for (int mt = 0; mt < 2; ++mt)
                #pragma unroll
                for (int r = 0; r < 4; ++r){
                    int b = mt*16 + kg*4 + r;
                    float ov = (a < 25 && b < 25) ? outer[((size_t)h*25 + a)*25 + b] : 0.f;
                    g[mt*4+r] = (b < 25) ? ex[mt*4+r]*inv + ov : 0.f;
                }
            uint2 pg0; pg0.x = pk2(g[0], g[1]); pg0.y = pk2(g[2], g[3]);
            uint2 pg1; pg1.x = pk2(g[4], g[5]); pg1.y = pk2(g[6], g[7]);
            P_G[nt][0] = pg0; P_G[nt][1] = pg1;
        }

        // ===== PV: C[hd][a] = v^T[hd][b] @ G^T[b][a], K=32 =====
        {
            bf16x8 fv0 = frag8(P_v[0][0], P_v[0][1], kg, l15);
            bf16x8 fv1 = frag8(P_v[1][0], P_v[1][1], kg, l15);
            bf16x8 fg0 = frag8(P_G[0][0], P_G[0][1], kg, l15);
            bf16x8 fg1 = frag8(P_G[1][0], P_G[1][1], kg, l15);
            f32x4 o[2][2];
            o[0][0] = MFMA(fv0, fg0, zf); o[0][1] = MFMA(fv0, fg1, zf);
            o[1][0] = MFMA(fv1, fg0, zf); o[1][1] = MFMA(fv1, fg1, zf);
            #pragma unroll
            for (int mt = 0; mt < 2; ++mt)
                #pragma unroll
                for (int nt = 0; nt < 2; ++nt){
                    int a = nt*16 + l15;
                    if (a < 25){
                        int coct = h*4 + mt*2 + (kg>>1);
                        u32* dst = (u32*)&opk[(coct*26 + a)*8 + (kg&1)*4];
                        dst[0] = pk2(o[mt][nt][0], o[mt][nt][1]);
                        dst[1] = pk2(o[mt][nt][2], o[mt][nt][3]);
                    }
                }
        }
    }
    __syncthreads();

    // ===== proj: out = Wproj @ o + bproj, K=256, cooperative (32 d per wave) =====
    {
        f32x4 pc[2][2];
        #pragma unroll
        for (int i = 0; i < 2; ++i){ pc[i][0] = zf; pc[i][1] = zf; }
        #pragma unroll
        for (int ks = 0; ks < 8; ++ks){
            bf16x8 pb0 = *(const bf16x8*)&opk[((ks*4+kg)*26 + l15)*8];
            bf16x8 pb1 = *(const bf16x8*)&opk[((ks*4+kg)*26 + 16 + l15)*8];
            #pragma unroll
            for (int i = 0; i < 2; ++i){
                bf16x8 aw = *(const bf16x8*)(wpk + 196608 +
                                (size_t)(w*32 + i*16 + l15)*256 + ks*32 + kg*8);
                pc[i][0] = MFMA(aw, pb0, pc[i][0]);
                pc[i][1] = MFMA(aw, pb1, pc[i][1]);
            }
        }
        #pragma unroll
        for (int i = 0; i < 2; ++i){
            const int d = w*32 + i*16 + kg*4;
            float b0 = bproj[d], b1 = bproj[d+1], b2 = bproj[d+2], b3 = bproj[d+3];
            #pragma unroll
            for (int nt = 0; nt < 2; ++nt){
                int v = nt*16 + l15;
                if (v < 25){
                    float* op = out + (size_t)n*768000 + (size_t)d*3000 + t*25 + v;
                    op[0]    = pc[i][nt][0] + b0;
                    op[3000] = pc[i][nt][1] + b1;
                    op[6000] = pc[i][nt][2] + b2;
                    op[9000] = pc[i][nt][3] + b3;
                }
            }
        }
    }
}

extern "C" void kernel_launch(void* const* d_in, const int* in_sizes, int n_in,
                              void* d_out, int out_size, void* d_ws, size_t ws_size,
                              hipStream_t stream) {
    (void)in_sizes; (void)n_in; (void)out_size; (void)ws_size;
    const float* x     = (const float*)d_in[0];
    const float* e     = (const float*)d_in[1];
    const float* Wkv   = (const float*)d_in[2];
    const float* Wq    = (const float*)d_in[3];
    const float* Wproj = (const float*)d_in[4];
    const float* bproj = (const float*)d_in[5];
    const float* rpe   = (const float*)d_in[6];
    const float* w1    = (const float*)d_in[7];
    const float* outer = (const float*)d_in[8];
    const float* alpha = (const float*)d_in[9];
    float* out = (float*)d_out;
    u16* wpk = (u16*)d_ws;

    prep_kernel<<<1030, 256, 0, stream>>>(Wkv, Wq, Wproj, rpe, w1, wpk);
    mhsa_main<<<32*120, 512, 0, stream>>>(x, e, outer, alpha, bproj, wpk, out);
}